// Round 2
// baseline (746.950 us; speedup 1.0000x reference)
//
#include <hip/hip_runtime.h>

static constexpr int Bc=4, Nc=512, Cc=128, EDc=64, ED2c=128, ATTc=8, INc=128;
static constexpr int Mc = Nc-1; // 511

// workspace layout (floats) — 460,288 floats = 1.84 MB
static constexpr int OFF_WCOMB = 0;                          // 4*128*128 = 65536
static constexpr int OFF_BCOMB = OFF_WCOMB + Bc*ED2c*Cc;     // +512
static constexpr int OFF_H     = OFF_BCOMB + Bc*ED2c;        // +131072 (4*512*64)
static constexpr int OFF_S     = OFF_H + Bc*Nc*EDc;          // +261632 (4*511*128), layout [b][m][j]
static constexpr int OFF_MAX   = OFF_S + Bc*Mc*INc;          // +512
static constexpr int OFF_DEN   = OFF_MAX + Bc*INc;           // +512
static constexpr int OFF_ACC   = OFF_DEN + Bc*INc;           // +512

// output layout (fp32): node_out[512] | tmp_p[4*128*511] | et_p[4*128*511]
static constexpr int OUT_TMP = Bc*INc;
static constexpr int OUT_ETP = OUT_TMP + Bc*INc*Mc;

__device__ __forceinline__ float gelu_f(float x){ return 0.5f*x*(1.0f + erff(x*0.70710678118654752f)); }
__device__ __forceinline__ float rho_f(float x){ return copysignf(sqrtf(fabsf(x)), x); }

// ---------------- K1: q = node[b,0]@Wq^T + b; Wcomb[e,c] = sum_a q[a,e]*Wk_w[a*128+e,c] ----------------
__global__ void __launch_bounds__(256) k1_qcomb(const float* __restrict__ node,
                         const float* __restrict__ Wq_w, const float* __restrict__ Wq_b,
                         const float* __restrict__ Wk_w, const float* __restrict__ Wk_b,
                         float* __restrict__ ws){
    int b = blockIdx.x;
    int t = threadIdx.x; // 256
    __shared__ float node0[Cc];
    __shared__ float q[ATTc*ED2c]; // 1024
    if (t < Cc) node0[t] = node[(size_t)(b*Nc)*Cc + t];
    __syncthreads();
    // q-phase: wave-parallel rows, coalesced float2 row reads + butterfly reduce
    int w = t >> 6, l = t & 63;
    for (int r = w*256; r < w*256 + 256; ++r){
        const float2 wv = *reinterpret_cast<const float2*>(Wq_w + (size_t)r*Cc + 2*l);
        float a = wv.x*node0[2*l] + wv.y*node0[2*l+1];
        #pragma unroll
        for (int off = 32; off; off >>= 1) a += __shfl_xor(a, off);
        if (l == 0) q[r] = a + Wq_b[r];
    }
    __syncthreads();
    float* Wcomb = ws + OFF_WCOMB + b*ED2c*Cc;
    for (int idx = t; idx < ED2c*Cc; idx += 256){   // coalesced (c = idx&127 contiguous per lane)
        int e = idx >> 7, c = idx & 127;
        float acc = 0.f;
        #pragma unroll
        for (int a = 0; a < ATTc; ++a)
            acc += q[a*ED2c + e] * Wk_w[(size_t)(a*ED2c + e)*Cc + c];
        Wcomb[idx] = acc;
    }
    if (t < ED2c){
        float acc = 0.f;
        #pragma unroll
        for (int a = 0; a < ATTc; ++a) acc += q[a*ED2c + t]*Wk_b[a*ED2c + t];
        ws[OFF_BCOMB + b*ED2c + t] = acc;
    }
    if (t < INc) ws[OFF_ACC + b*INc + t] = 0.f;
}

// ---- coalesced float4 stage of [nrows x 64] chunk into padded LDS ([...][65]) ----
__device__ __forceinline__ void stage_rows(const float* __restrict__ src, int rs, int c0,
                                           float (*W)[65], int rowbase, int nrows, int t){
    int nf4 = nrows*16;
    for (int f = t; f < nf4; f += 128){
        int row = f >> 4, cp = (f & 15) << 2;
        float4 v = *reinterpret_cast<const float4*>(src + (size_t)row*rs + c0 + cp);
        float* d = &W[rowbase + row][cp];
        d[0]=v.x; d[1]=v.y; d[2]=v.z; d[3]=v.w;
    }
}

// ---------------- K2: per 8 n-rows: qk, ew/eb, h  AND  S = h(1:) @ Wa^T ----------------
__global__ void __launch_bounds__(128) k2_h_s(const float* __restrict__ node,
            const float* __restrict__ edge, const float* __restrict__ emb,
            const float* __restrict__ Wew, const float* __restrict__ Web,
            const float* __restrict__ Wa, float* __restrict__ ws){
    __shared__ float Wsh[128][65];   // 33,280 B staged-weight buffer (reused 4x)
    __shared__ float nsh[8][128];
    __shared__ float e0sh[8][64];
    __shared__ float emsh[8][64];
    __shared__ float qksh[8][128];
    __shared__ float ewsh[8][64];
    __shared__ float ebsh[8][64];
    __shared__ float hsh[8][64];
    int blk = blockIdx.x;
    int b = blk >> 6, n0 = (blk & 63)*8;
    int t = threadIdx.x; // 0..127
    // flat float4 staging (rows contiguous in memory, fully coalesced)
    {
        const float4* np = reinterpret_cast<const float4*>(node + (size_t)(b*Nc + n0)*Cc);
        float4* ns = reinterpret_cast<float4*>(&nsh[0][0]);
        ns[t] = np[t]; ns[t+128] = np[t+128];                     // 1024 floats
        const float4* ep = reinterpret_cast<const float4*>(edge + ((size_t)b*Nc*Nc + n0)*EDc);
        reinterpret_cast<float4*>(&e0sh[0][0])[t] = ep[t];        // 512 floats
        const float4* mp = reinterpret_cast<const float4*>(emb + ((size_t)b*Nc*Nc + n0)*EDc);
        reinterpret_cast<float4*>(&emsh[0][0])[t] = mp[t];
    }
    const float* WcombB = ws + OFF_WCOMB + b*ED2c*Cc;
    stage_rows(WcombB, Cc, 0, Wsh, 0, 128, t);
    __syncthreads();
    // qk[mi][t] = nsh[mi] . Wcomb[t] + bcomb[t]
    float acc[8];
    float bc = ws[OFF_BCOMB + b*ED2c + t];
    #pragma unroll
    for (int mi = 0; mi < 8; ++mi) acc[mi] = bc;
    for (int c = 0; c < 64; c += 4){
        float w0=Wsh[t][c], w1=Wsh[t][c+1], w2=Wsh[t][c+2], w3=Wsh[t][c+3];
        #pragma unroll
        for (int mi = 0; mi < 8; ++mi){
            float4 nv = *reinterpret_cast<const float4*>(&nsh[mi][c]);
            acc[mi] += nv.x*w0 + nv.y*w1 + nv.z*w2 + nv.w*w3;
        }
    }
    __syncthreads();
    stage_rows(WcombB, Cc, 64, Wsh, 0, 128, t);
    __syncthreads();
    for (int c = 0; c < 64; c += 4){
        float w0=Wsh[t][c], w1=Wsh[t][c+1], w2=Wsh[t][c+2], w3=Wsh[t][c+3];
        #pragma unroll
        for (int mi = 0; mi < 8; ++mi){
            float4 nv = *reinterpret_cast<const float4*>(&nsh[mi][64 + c]);
            acc[mi] += nv.x*w0 + nv.y*w1 + nv.z*w2 + nv.w*w3;
        }
    }
    #pragma unroll
    for (int mi = 0; mi < 8; ++mi) qksh[mi][t] = acc[mi];
    __syncthreads();
    // ew (t<64: Wew row t) / eb (t>=64: Web row t-64)
    stage_rows(Wew, EDc, 0, Wsh, 0, 64, t);
    stage_rows(Web, EDc, 0, Wsh, 64, 64, t);
    __syncthreads();
    {
        float dv[8];
        #pragma unroll
        for (int mi = 0; mi < 8; ++mi) dv[mi] = 0.f;
        for (int c = 0; c < 64; c += 4){
            float w0=Wsh[t][c], w1=Wsh[t][c+1], w2=Wsh[t][c+2], w3=Wsh[t][c+3];
            #pragma unroll
            for (int mi = 0; mi < 8; ++mi){
                float4 ev = *reinterpret_cast<const float4*>(&e0sh[mi][c]);
                dv[mi] += ev.x*w0 + ev.y*w1 + ev.z*w2 + ev.w*w3;
            }
        }
        int d = t & 63;
        if (t < 64){
            #pragma unroll
            for (int mi = 0; mi < 8; ++mi) ewsh[mi][d] = dv[mi];
        } else {
            #pragma unroll
            for (int mi = 0; mi < 8; ++mi) ebsh[mi][d] = dv[mi];
        }
    }
    __syncthreads();
    // h = gelu(rho(qk[:64]*ew) + eb + qk[64:] + em); stage Wa concurrently (Wsh is free)
    {
        int d = t & 63, g = t >> 6;
        #pragma unroll
        for (int k = 0; k < 4; ++k){
            int mi = g*4 + k;
            float x = rho_f(qksh[mi][d]*ewsh[mi][d]) + ebsh[mi][d] + qksh[mi][64+d] + emsh[mi][d];
            float h = gelu_f(x);
            hsh[mi][d] = h;
            ws[OFF_H + (size_t)(b*Nc + n0 + mi)*EDc + d] = h;
        }
    }
    stage_rows(Wa, EDc, 0, Wsh, 0, 128, t);
    __syncthreads();
    // S[b][m][j=t] = hsh[mi] . Wa[t]   (m = n0+mi-1; row n=0 excluded) — coalesced store
    #pragma unroll
    for (int mi = 0; mi < 8; ++mi){
        int m = n0 + mi - 1;
        if (m < 0) continue;
        float s = 0.f;
        for (int c = 0; c < 64; c += 4){
            float w0=Wsh[t][c], w1=Wsh[t][c+1], w2=Wsh[t][c+2], w3=Wsh[t][c+3];
            float4 hv = *reinterpret_cast<const float4*>(&hsh[mi][c]);
            s += hv.x*w0 + hv.y*w1 + hv.z*w2 + hv.w*w3;
        }
        ws[OFF_S + ((size_t)(b*Mc + m))*INc + t] = s;
    }
}

// ---------------- K3: softmax stats per (b,j) over m (reads materialized S) ----------------
__global__ void k3_stats(float* __restrict__ ws){
    int bj = blockIdx.x;              // b*128 + j
    int b = bj >> 7, j = bj & 127;
    int l = threadIdx.x;              // 0..63
    float sv[8];
    float mx = -1e30f;
    #pragma unroll
    for (int i = 0; i < 8; ++i){
        int m = i*64 + l;
        float s = -1e30f;
        if (m < Mc) s = ws[OFF_S + ((size_t)(b*Mc + m))*INc + j];
        sv[i] = s; mx = fmaxf(mx, s);
    }
    #pragma unroll
    for (int off = 32; off; off >>= 1) mx = fmaxf(mx, __shfl_xor(mx, off));
    float sum = 0.f;
    #pragma unroll
    for (int i = 0; i < 8; ++i) if (sv[i] > -1e29f) sum += expf(sv[i] - mx);
    #pragma unroll
    for (int off = 32; off; off >>= 1) sum += __shfl_xor(sum, off);
    if (l == 0){ ws[OFF_MAX + bj] = mx; ws[OFF_DEN + bj] = 1.0f/sum; }
}

// ---- coalesced float4 stage of [128 x 32] weight chunk into padded LDS ([...][33]) ----
__device__ __forceinline__ void stage32(const float* __restrict__ src, int rs, int c0,
                                        float (*W)[33], int t){
    #pragma unroll
    for (int rep = 0; rep < 8; ++rep){
        int f = t + rep*128;
        int row = f >> 3, cp = (f & 7) << 2;
        float4 v = *reinterpret_cast<const float4*>(src + (size_t)row*rs + c0 + cp);
        float* d = &W[row][cp];
        d[0]=v.x; d[1]=v.y; d[2]=v.z; d[3]=v.w;
    }
}

// ---------------- K4: 4 m-rows per block: alpha (from S), et, nt, h1-gelu, h2, outputs ----------------
__global__ void __launch_bounds__(128) k4_mlp(const float* __restrict__ node,
        const float* __restrict__ et_w, const float* __restrict__ et_b,
        const float* __restrict__ nt_w, const float* __restrict__ nt_b,
        const float* __restrict__ h1_w, const float* __restrict__ h1_b,
        const float* __restrict__ h2_w, const float* __restrict__ h2_b,
        float* __restrict__ ws, float* __restrict__ out){
    constexpr int TM = 4;
    __shared__ float Wsh[128][33];   // 16.9 KB chunk buffer -> total LDS ~26 KB -> 2+ blocks/CU
    __shared__ float esh[TM][64];
    __shared__ float nsh[TM][128];
    __shared__ float csh[TM][256];
    __shared__ float gsh[TM][128];
    int blk = blockIdx.x;
    int b = blk >> 7, m0 = (blk & 127)*TM;
    int t = threadIdx.x;             // j
    int nm = Mc - m0; if (nm > TM) nm = TM;
    if (m0 + TM <= Nc - 1){          // fast path: rows m0+1..m0+TM all valid -> flat f4 copy
        const float4* hp = reinterpret_cast<const float4*>(ws + OFF_H + (size_t)(b*Nc + m0 + 1)*EDc);
        if (t < 64) reinterpret_cast<float4*>(&esh[0][0])[t] = hp[t];     // 256 floats
        const float4* np = reinterpret_cast<const float4*>(node + (size_t)(b*Nc + m0 + 1)*Cc);
        reinterpret_cast<float4*>(&nsh[0][0])[t] = np[t];                 // 512 floats
    } else {
        for (int i = t; i < TM*EDc; i += 128){
            int mi = i >> 6, row = m0 + mi + 1; if (row > Nc-1) row = Nc-1;
            esh[mi][i & 63] = ws[OFF_H + (size_t)(b*Nc + row)*EDc + (i & 63)];
        }
        for (int i = t; i < TM*Cc; i += 128){
            int mi = i >> 7, row = m0 + mi + 1; if (row > Nc-1) row = Nc-1;
            nsh[mi][i & 127] = node[(size_t)(b*Nc + row)*Cc + (i & 127)];
        }
    }
    float mx  = ws[OFF_MAX + b*INc + t];
    float inv = ws[OFF_DEN + b*INc + t];
    float alpha[TM];
    #pragma unroll
    for (int mi = 0; mi < TM; ++mi){
        float a = 0.f;
        if (mi < nm){
            float s = ws[OFF_S + ((size_t)(b*Mc + m0 + mi))*INc + t];  // coalesced
            a = expf(s - mx)*inv;
        }
        alpha[mi] = a;
    }
    float acc[TM];
    // ---- et ----
    #pragma unroll
    for (int mi = 0; mi < TM; ++mi) acc[mi] = 0.f;
    for (int cc = 0; cc < 64; cc += 32){
        __syncthreads();
        stage32(et_w, EDc, cc, Wsh, t);
        __syncthreads();
        for (int c = 0; c < 32; c += 4){
            float w0=Wsh[t][c], w1=Wsh[t][c+1], w2=Wsh[t][c+2], w3=Wsh[t][c+3];
            #pragma unroll
            for (int mi = 0; mi < TM; ++mi){
                float4 v = *reinterpret_cast<const float4*>(&esh[mi][cc + c]);
                acc[mi] += v.x*w0 + v.y*w1 + v.z*w2 + v.w*w3;
            }
        }
    }
    {
        float bb = et_b[t];
        #pragma unroll
        for (int mi = 0; mi < TM; ++mi){
            float v = (acc[mi] + bb)*alpha[mi];
            csh[mi][t] = v;
            if (mi < nm) out[OUT_ETP + (size_t)(b*INc + t)*Mc + (m0 + mi)] = v;
        }
    }
    // ---- nt ----
    #pragma unroll
    for (int mi = 0; mi < TM; ++mi) acc[mi] = 0.f;
    for (int cc = 0; cc < 128; cc += 32){
        __syncthreads();
        stage32(nt_w, Cc, cc, Wsh, t);
        __syncthreads();
        for (int c = 0; c < 32; c += 4){
            float w0=Wsh[t][c], w1=Wsh[t][c+1], w2=Wsh[t][c+2], w3=Wsh[t][c+3];
            #pragma unroll
            for (int mi = 0; mi < TM; ++mi){
                float4 v = *reinterpret_cast<const float4*>(&nsh[mi][cc + c]);
                acc[mi] += v.x*w0 + v.y*w1 + v.z*w2 + v.w*w3;
            }
        }
    }
    {
        float bb = nt_b[t];
        #pragma unroll
        for (int mi = 0; mi < TM; ++mi) csh[mi][INc + t] = (acc[mi] + bb)*alpha[mi];
    }
    // ---- h1 + gelu ----
    #pragma unroll
    for (int mi = 0; mi < TM; ++mi) acc[mi] = 0.f;
    for (int cc = 0; cc < 256; cc += 32){
        __syncthreads();   // also publishes csh on first pass
        stage32(h1_w, 2*INc, cc, Wsh, t);
        __syncthreads();
        for (int c = 0; c < 32; c += 4){
            float w0=Wsh[t][c], w1=Wsh[t][c+1], w2=Wsh[t][c+2], w3=Wsh[t][c+3];
            #pragma unroll
            for (int mi = 0; mi < TM; ++mi){
                float4 v = *reinterpret_cast<const float4*>(&csh[mi][cc + c]);
                acc[mi] += v.x*w0 + v.y*w1 + v.z*w2 + v.w*w3;
            }
        }
    }
    {
        float bb = h1_b[t];
        #pragma unroll
        for (int mi = 0; mi < TM; ++mi) gsh[mi][t] = gelu_f(acc[mi] + bb);
    }
    // ---- h2 + outputs ----
    #pragma unroll
    for (int mi = 0; mi < TM; ++mi) acc[mi] = 0.f;
    for (int cc = 0; cc < 128; cc += 32){
        __syncthreads();   // also publishes gsh on first pass
        stage32(h2_w, INc, cc, Wsh, t);
        __syncthreads();
        for (int c = 0; c < 32; c += 4){
            float w0=Wsh[t][c], w1=Wsh[t][c+1], w2=Wsh[t][c+2], w3=Wsh[t][c+3];
            #pragma unroll
            for (int mi = 0; mi < TM; ++mi){
                float4 v = *reinterpret_cast<const float4*>(&gsh[mi][cc + c]);
                acc[mi] += v.x*w0 + v.y*w1 + v.z*w2 + v.w*w3;
            }
        }
    }
    {
        float bb = h2_b[t];
        float lsum = 0.f;
        #pragma unroll
        for (int mi = 0; mi < TM; ++mi){
            if (mi < nm){
                float v = acc[mi] + bb;
                out[OUT_TMP + (size_t)(b*INc + t)*Mc + (m0 + mi)] = v;
                lsum += v;
            }
        }
        atomicAdd(&ws[OFF_ACC + b*INc + t], lsum);
    }
}

// ---------------- K5: node_out = acc * 2/sqrt(C) ----------------
__global__ void k5_nodeout(const float* __restrict__ ws, float* __restrict__ out){
    int i = blockIdx.x*256 + threadIdx.x;
    if (i < Bc*INc) out[i] = ws[OFF_ACC + i]*0.17677669529663687f;
}

extern "C" void kernel_launch(void* const* d_in, const int* in_sizes, int n_in,
                              void* d_out, int out_size, void* d_ws, size_t ws_size,
                              hipStream_t stream){
    const float* node = (const float*)d_in[0];
    const float* edge = (const float*)d_in[1];
    const float* emb  = (const float*)d_in[2];
    const float* Wq_w = (const float*)d_in[3];
    const float* Wq_b = (const float*)d_in[4];
    const float* Wk_w = (const float*)d_in[5];
    const float* Wk_b = (const float*)d_in[6];
    const float* Wew  = (const float*)d_in[7];
    const float* Web  = (const float*)d_in[8];
    const float* Wa   = (const float*)d_in[9];
    const float* nt_w = (const float*)d_in[10];
    const float* nt_b = (const float*)d_in[11];
    const float* et_w = (const float*)d_in[12];
    const float* et_b = (const float*)d_in[13];
    const float* h1_w = (const float*)d_in[14];
    const float* h1_b = (const float*)d_in[15];
    const float* h2_w = (const float*)d_in[16];
    const float* h2_b = (const float*)d_in[17];
    float* ws = (float*)d_ws;
    float* out = (float*)d_out;

    k1_qcomb<<<Bc, 256, 0, stream>>>(node, Wq_w, Wq_b, Wk_w, Wk_b, ws);
    k2_h_s<<<Bc*64, 128, 0, stream>>>(node, edge, emb, Wew, Web, Wa, ws);
    k3_stats<<<Bc*INc, 64, 0, stream>>>(ws);
    k4_mlp<<<Bc*128, 128, 0, stream>>>(node, et_w, et_b, nt_w, nt_b,
                                       h1_w, h1_b, h2_w, h2_b, ws, out);
    k5_nodeout<<<2, 256, 0, stream>>>(ws, out);
}

// Round 3
// 622.173 us; speedup vs baseline: 1.2005x; 1.2005x over previous
//
#include <hip/hip_runtime.h>

static constexpr int Bc=4, Nc=512, Cc=128, EDc=64, ED2c=128, ATTc=8, INc=128;
static constexpr int Mc = Nc-1; // 511

// workspace layout (floats)
static constexpr int OFF_WCOMB = 0;                          // 4*128*128 = 65536
static constexpr int OFF_BCOMB = OFF_WCOMB + Bc*ED2c*Cc;     // +512
static constexpr int OFF_H     = OFF_BCOMB + Bc*ED2c;        // +131072 (4*512*64)
static constexpr int OFF_S     = OFF_H + Bc*Nc*EDc;          // +261632 (4*511*128), layout [b][m][j]
static constexpr int OFF_MAX   = OFF_S + Bc*Mc*INc;          // +512
static constexpr int OFF_DEN   = OFF_MAX + Bc*INc;           // +512
static constexpr int OFF_ACC   = OFF_DEN + Bc*INc;           // +512
static constexpr int OFF_Q     = OFF_ACC + Bc*INc;           // +4096 (4*1024)

// output layout (fp32): node_out[512] | tmp_p[4*128*511] | et_p[4*128*511]
static constexpr int OUT_TMP = Bc*INc;
static constexpr int OUT_ETP = OUT_TMP + Bc*INc*Mc;

__device__ __forceinline__ float gelu_f(float x){ return 0.5f*x*(1.0f + erff(x*0.70710678118654752f)); }
__device__ __forceinline__ float rho_f(float x){ return copysignf(sqrtf(fabsf(x)), x); }

// ---------------- K1a: q[b][r] = node[b,0] . Wq_w[r] + Wq_b[r]  (one row per wave-step) ----------------
__global__ void __launch_bounds__(256) k1a_q(const float* __restrict__ node,
                         const float* __restrict__ Wq_w, const float* __restrict__ Wq_b,
                         float* __restrict__ ws){
    int blk = blockIdx.x;            // Bc*16 = 64 blocks
    int b = blk >> 4;
    int t = threadIdx.x;             // 256 = 4 waves
    int w = t >> 6, l = t & 63;
    __shared__ float node0[Cc];
    if (t < Cc) node0[t] = node[(size_t)(b*Nc)*Cc + t];
    __syncthreads();
    int rbase = (blk & 15)*64 + w*16;
    float n0 = node0[2*l], n1 = node0[2*l+1];
    #pragma unroll
    for (int i = 0; i < 16; ++i){
        int r = rbase + i;
        const float2 wv = *reinterpret_cast<const float2*>(Wq_w + (size_t)r*Cc + 2*l);
        float a = wv.x*n0 + wv.y*n1;
        #pragma unroll
        for (int off = 32; off; off >>= 1) a += __shfl_xor(a, off);
        if (l == 0) ws[OFF_Q + b*1024 + r] = a + Wq_b[r];
    }
}

// ---------------- K1b: Wcomb[b][e][c] = sum_a q[a*128+e]*Wk_w[(a*128+e)*128+c]; bcomb; acc-zero --------
__global__ void __launch_bounds__(256) k1b_comb(const float* __restrict__ Wk_w,
                         const float* __restrict__ Wk_b, float* __restrict__ ws){
    int blk = blockIdx.x;            // Bc*8 = 32 blocks
    int b = blk >> 3;
    int e0 = (blk & 7)*16;
    int t = threadIdx.x;             // 256
    __shared__ float qs[ATTc*16];    // q[a][e-e0]
    if (t < 128){
        int a = t >> 4, ei = t & 15;
        qs[a*16 + ei] = ws[OFF_Q + b*1024 + a*ED2c + e0 + ei];
    }
    __syncthreads();
    if (t < 16){
        float bc = 0.f;
        #pragma unroll
        for (int a = 0; a < ATTc; ++a) bc += qs[a*16 + t]*Wk_b[a*ED2c + e0 + t];
        ws[OFF_BCOMB + b*ED2c + e0 + t] = bc;
    }
    if ((blk & 7) == 0 && t >= 128) ws[OFF_ACC + b*INc + (t-128)] = 0.f;
    int c = t & 127;
    int eh = t >> 7;                 // 0 or 1
    #pragma unroll
    for (int it = 0; it < 8; ++it){
        int ei = eh + it*2;
        int e = e0 + ei;
        float acc = 0.f;
        #pragma unroll
        for (int a = 0; a < ATTc; ++a)
            acc += qs[a*16 + ei] * Wk_w[(size_t)(a*ED2c + e)*Cc + c];
        ws[OFF_WCOMB + (size_t)b*ED2c*Cc + e*Cc + c] = acc;
    }
}

// ---- coalesced float4 stage of [nrows x 64] chunk into padded LDS ([...][65]) ----
__device__ __forceinline__ void stage_rows(const float* __restrict__ src, int rs, int c0,
                                           float (*W)[65], int rowbase, int nrows, int t){
    int nf4 = nrows*16;
    for (int f = t; f < nf4; f += 128){
        int row = f >> 4, cp = (f & 15) << 2;
        float4 v = *reinterpret_cast<const float4*>(src + (size_t)row*rs + c0 + cp);
        float* d = &W[rowbase + row][cp];
        d[0]=v.x; d[1]=v.y; d[2]=v.z; d[3]=v.w;
    }
}

// ---------------- K2: per 8 n-rows: qk, ew/eb, h  AND  S = h(1:) @ Wa^T ----------------
__global__ void __launch_bounds__(128) k2_h_s(const float* __restrict__ node,
            const float* __restrict__ edge, const float* __restrict__ emb,
            const float* __restrict__ Wew, const float* __restrict__ Web,
            const float* __restrict__ Wa, float* __restrict__ ws){
    __shared__ float Wsh[128][65];
    __shared__ float nsh[8][128];
    __shared__ float e0sh[8][64];
    __shared__ float emsh[8][64];
    __shared__ float qksh[8][128];
    __shared__ float ewsh[8][64];
    __shared__ float ebsh[8][64];
    __shared__ float hsh[8][64];
    int blk = blockIdx.x;
    int b = blk >> 6, n0 = (blk & 63)*8;
    int t = threadIdx.x; // 0..127
    {
        const float4* np = reinterpret_cast<const float4*>(node + (size_t)(b*Nc + n0)*Cc);
        float4* ns = reinterpret_cast<float4*>(&nsh[0][0]);
        ns[t] = np[t]; ns[t+128] = np[t+128];
        const float4* ep = reinterpret_cast<const float4*>(edge + ((size_t)b*Nc*Nc + n0)*EDc);
        reinterpret_cast<float4*>(&e0sh[0][0])[t] = ep[t];
        const float4* mp = reinterpret_cast<const float4*>(emb + ((size_t)b*Nc*Nc + n0)*EDc);
        reinterpret_cast<float4*>(&emsh[0][0])[t] = mp[t];
    }
    const float* WcombB = ws + OFF_WCOMB + (size_t)b*ED2c*Cc;
    stage_rows(WcombB, Cc, 0, Wsh, 0, 128, t);
    __syncthreads();
    float acc[8];
    float bc = ws[OFF_BCOMB + b*ED2c + t];
    #pragma unroll
    for (int mi = 0; mi < 8; ++mi) acc[mi] = bc;
    for (int c = 0; c < 64; c += 4){
        float w0=Wsh[t][c], w1=Wsh[t][c+1], w2=Wsh[t][c+2], w3=Wsh[t][c+3];
        #pragma unroll
        for (int mi = 0; mi < 8; ++mi){
            float4 nv = *reinterpret_cast<const float4*>(&nsh[mi][c]);
            acc[mi] += nv.x*w0 + nv.y*w1 + nv.z*w2 + nv.w*w3;
        }
    }
    __syncthreads();
    stage_rows(WcombB, Cc, 64, Wsh, 0, 128, t);
    __syncthreads();
    for (int c = 0; c < 64; c += 4){
        float w0=Wsh[t][c], w1=Wsh[t][c+1], w2=Wsh[t][c+2], w3=Wsh[t][c+3];
        #pragma unroll
        for (int mi = 0; mi < 8; ++mi){
            float4 nv = *reinterpret_cast<const float4*>(&nsh[mi][64 + c]);
            acc[mi] += nv.x*w0 + nv.y*w1 + nv.z*w2 + nv.w*w3;
        }
    }
    #pragma unroll
    for (int mi = 0; mi < 8; ++mi) qksh[mi][t] = acc[mi];
    __syncthreads();
    stage_rows(Wew, EDc, 0, Wsh, 0, 64, t);
    stage_rows(Web, EDc, 0, Wsh, 64, 64, t);
    __syncthreads();
    {
        float dv[8];
        #pragma unroll
        for (int mi = 0; mi < 8; ++mi) dv[mi] = 0.f;
        for (int c = 0; c < 64; c += 4){
            float w0=Wsh[t][c], w1=Wsh[t][c+1], w2=Wsh[t][c+2], w3=Wsh[t][c+3];
            #pragma unroll
            for (int mi = 0; mi < 8; ++mi){
                float4 ev = *reinterpret_cast<const float4*>(&e0sh[mi][c]);
                dv[mi] += ev.x*w0 + ev.y*w1 + ev.z*w2 + ev.w*w3;
            }
        }
        int d = t & 63;
        if (t < 64){
            #pragma unroll
            for (int mi = 0; mi < 8; ++mi) ewsh[mi][d] = dv[mi];
        } else {
            #pragma unroll
            for (int mi = 0; mi < 8; ++mi) ebsh[mi][d] = dv[mi];
        }
    }
    __syncthreads();
    {
        int d = t & 63, g = t >> 6;
        #pragma unroll
        for (int k = 0; k < 4; ++k){
            int mi = g*4 + k;
            float x = rho_f(qksh[mi][d]*ewsh[mi][d]) + ebsh[mi][d] + qksh[mi][64+d] + emsh[mi][d];
            float h = gelu_f(x);
            hsh[mi][d] = h;
            ws[OFF_H + (size_t)(b*Nc + n0 + mi)*EDc + d] = h;
        }
    }
    stage_rows(Wa, EDc, 0, Wsh, 0, 128, t);
    __syncthreads();
    #pragma unroll
    for (int mi = 0; mi < 8; ++mi){
        int m = n0 + mi - 1;
        if (m < 0) continue;
        float s = 0.f;
        for (int c = 0; c < 64; c += 4){
            float w0=Wsh[t][c], w1=Wsh[t][c+1], w2=Wsh[t][c+2], w3=Wsh[t][c+3];
            float4 hv = *reinterpret_cast<const float4*>(&hsh[mi][c]);
            s += hv.x*w0 + hv.y*w1 + hv.z*w2 + hv.w*w3;
        }
        ws[OFF_S + ((size_t)(b*Mc + m))*INc + t] = s;
    }
}

// ---------------- K3: softmax stats per b; thread=j, coalesced sweep over m ----------------
__global__ void __launch_bounds__(128) k3_stats(float* __restrict__ ws){
    int b = blockIdx.x;
    int t = threadIdx.x;             // j
    const float* S = ws + OFF_S + (size_t)b*Mc*INc;
    float mx = -1e30f;
    for (int m = 0; m < Mc; ++m) mx = fmaxf(mx, S[(size_t)m*INc + t]);
    float sum = 0.f;
    for (int m = 0; m < Mc; ++m) sum += expf(S[(size_t)m*INc + t] - mx);
    ws[OFF_MAX + b*INc + t] = mx;
    ws[OFF_DEN + b*INc + t] = 1.0f/sum;
}

// ---- coalesced float4 stage of [128 x 32] weight chunk into padded LDS ([...][33]) ----
__device__ __forceinline__ void stage32(const float* __restrict__ src, int rs, int c0,
                                        float (*W)[33], int t){
    #pragma unroll
    for (int rep = 0; rep < 8; ++rep){
        int f = t + rep*128;
        int row = f >> 3, cp = (f & 7) << 2;
        float4 v = *reinterpret_cast<const float4*>(src + (size_t)row*rs + c0 + cp);
        float* d = &W[row][cp];
        d[0]=v.x; d[1]=v.y; d[2]=v.z; d[3]=v.w;
    }
}

// ---------------- K4: 4 m-rows per block: alpha (from S), et, nt, h1-gelu, h2, outputs ----------------
__global__ void __launch_bounds__(128) k4_mlp(const float* __restrict__ node,
        const float* __restrict__ et_w, const float* __restrict__ et_b,
        const float* __restrict__ nt_w, const float* __restrict__ nt_b,
        const float* __restrict__ h1_w, const float* __restrict__ h1_b,
        const float* __restrict__ h2_w, const float* __restrict__ h2_b,
        float* __restrict__ ws, float* __restrict__ out){
    constexpr int TM = 4;
    __shared__ float Wsh[128][33];
    __shared__ float esh[TM][64];
    __shared__ float nsh[TM][128];
    __shared__ float csh[TM][256];
    __shared__ float gsh[TM][128];
    int blk = blockIdx.x;
    int b = blk >> 7, m0 = (blk & 127)*TM;
    int t = threadIdx.x;             // j
    int nm = Mc - m0; if (nm > TM) nm = TM;
    if (m0 + TM <= Nc - 1){
        const float4* hp = reinterpret_cast<const float4*>(ws + OFF_H + (size_t)(b*Nc + m0 + 1)*EDc);
        if (t < 64) reinterpret_cast<float4*>(&esh[0][0])[t] = hp[t];
        const float4* np = reinterpret_cast<const float4*>(node + (size_t)(b*Nc + m0 + 1)*Cc);
        reinterpret_cast<float4*>(&nsh[0][0])[t] = np[t];
    } else {
        for (int i = t; i < TM*EDc; i += 128){
            int mi = i >> 6, row = m0 + mi + 1; if (row > Nc-1) row = Nc-1;
            esh[mi][i & 63] = ws[OFF_H + (size_t)(b*Nc + row)*EDc + (i & 63)];
        }
        for (int i = t; i < TM*Cc; i += 128){
            int mi = i >> 7, row = m0 + mi + 1; if (row > Nc-1) row = Nc-1;
            nsh[mi][i & 127] = node[(size_t)(b*Nc + row)*Cc + (i & 127)];
        }
    }
    float mx  = ws[OFF_MAX + b*INc + t];
    float inv = ws[OFF_DEN + b*INc + t];
    float alpha[TM];
    #pragma unroll
    for (int mi = 0; mi < TM; ++mi){
        float a = 0.f;
        if (mi < nm){
            float s = ws[OFF_S + ((size_t)(b*Mc + m0 + mi))*INc + t];
            a = expf(s - mx)*inv;
        }
        alpha[mi] = a;
    }
    float acc[TM];
    // ---- et ----
    #pragma unroll
    for (int mi = 0; mi < TM; ++mi) acc[mi] = 0.f;
    for (int cc = 0; cc < 64; cc += 32){
        __syncthreads();
        stage32(et_w, EDc, cc, Wsh, t);
        __syncthreads();
        for (int c = 0; c < 32; c += 4){
            float w0=Wsh[t][c], w1=Wsh[t][c+1], w2=Wsh[t][c+2], w3=Wsh[t][c+3];
            #pragma unroll
            for (int mi = 0; mi < TM; ++mi){
                float4 v = *reinterpret_cast<const float4*>(&esh[mi][cc + c]);
                acc[mi] += v.x*w0 + v.y*w1 + v.z*w2 + v.w*w3;
            }
        }
    }
    {
        float bb = et_b[t];
        #pragma unroll
        for (int mi = 0; mi < TM; ++mi){
            float v = (acc[mi] + bb)*alpha[mi];
            csh[mi][t] = v;
            if (mi < nm) out[OUT_ETP + (size_t)(b*INc + t)*Mc + (m0 + mi)] = v;
        }
    }
    // ---- nt ----
    #pragma unroll
    for (int mi = 0; mi < TM; ++mi) acc[mi] = 0.f;
    for (int cc = 0; cc < 128; cc += 32){
        __syncthreads();
        stage32(nt_w, Cc, cc, Wsh, t);
        __syncthreads();
        for (int c = 0; c < 32; c += 4){
            float w0=Wsh[t][c], w1=Wsh[t][c+1], w2=Wsh[t][c+2], w3=Wsh[t][c+3];
            #pragma unroll
            for (int mi = 0; mi < TM; ++mi){
                float4 v = *reinterpret_cast<const float4*>(&nsh[mi][cc + c]);
                acc[mi] += v.x*w0 + v.y*w1 + v.z*w2 + v.w*w3;
            }
        }
    }
    {
        float bb = nt_b[t];
        #pragma unroll
        for (int mi = 0; mi < TM; ++mi) csh[mi][INc + t] = (acc[mi] + bb)*alpha[mi];
    }
    // ---- h1 + gelu ----
    #pragma unroll
    for (int mi = 0; mi < TM; ++mi) acc[mi] = 0.f;
    for (int cc = 0; cc < 256; cc += 32){
        __syncthreads();
        stage32(h1_w, 2*INc, cc, Wsh, t);
        __syncthreads();
        for (int c = 0; c < 32; c += 4){
            float w0=Wsh[t][c], w1=Wsh[t][c+1], w2=Wsh[t][c+2], w3=Wsh[t][c+3];
            #pragma unroll
            for (int mi = 0; mi < TM; ++mi){
                float4 v = *reinterpret_cast<const float4*>(&csh[mi][cc + c]);
                acc[mi] += v.x*w0 + v.y*w1 + v.z*w2 + v.w*w3;
            }
        }
    }
    {
        float bb = h1_b[t];
        #pragma unroll
        for (int mi = 0; mi < TM; ++mi) gsh[mi][t] = gelu_f(acc[mi] + bb);
    }
    // ---- h2 + outputs ----
    #pragma unroll
    for (int mi = 0; mi < TM; ++mi) acc[mi] = 0.f;
    for (int cc = 0; cc < 128; cc += 32){
        __syncthreads();
        stage32(h2_w, INc, cc, Wsh, t);
        __syncthreads();
        for (int c = 0; c < 32; c += 4){
            float w0=Wsh[t][c], w1=Wsh[t][c+1], w2=Wsh[t][c+2], w3=Wsh[t][c+3];
            #pragma unroll
            for (int mi = 0; mi < TM; ++mi){
                float4 v = *reinterpret_cast<const float4*>(&gsh[mi][cc + c]);
                acc[mi] += v.x*w0 + v.y*w1 + v.z*w2 + v.w*w3;
            }
        }
    }
    {
        float bb = h2_b[t];
        float lsum = 0.f;
        #pragma unroll
        for (int mi = 0; mi < TM; ++mi){
            if (mi < nm){
                float v = acc[mi] + bb;
                out[OUT_TMP + (size_t)(b*INc + t)*Mc + (m0 + mi)] = v;
                lsum += v;
            }
        }
        atomicAdd(&ws[OFF_ACC + b*INc + t], lsum);
    }
}

// ---------------- K5: node_out = acc * 2/sqrt(C) ----------------
__global__ void k5_nodeout(const float* __restrict__ ws, float* __restrict__ out){
    int i = blockIdx.x*256 + threadIdx.x;
    if (i < Bc*INc) out[i] = ws[OFF_ACC + i]*0.17677669529663687f;
}

extern "C" void kernel_launch(void* const* d_in, const int* in_sizes, int n_in,
                              void* d_out, int out_size, void* d_ws, size_t ws_size,
                              hipStream_t stream){
    const float* node = (const float*)d_in[0];
    const float* edge = (const float*)d_in[1];
    const float* emb  = (const float*)d_in[2];
    const float* Wq_w = (const float*)d_in[3];
    const float* Wq_b = (const float*)d_in[4];
    const float* Wk_w = (const float*)d_in[5];
    const float* Wk_b = (const float*)d_in[6];
    const float* Wew  = (const float*)d_in[7];
    const float* Web  = (const float*)d_in[8];
    const float* Wa   = (const float*)d_in[9];
    const float* nt_w = (const float*)d_in[10];
    const float* nt_b = (const float*)d_in[11];
    const float* et_w = (const float*)d_in[12];
    const float* et_b = (const float*)d_in[13];
    const float* h1_w = (const float*)d_in[14];
    const float* h1_b = (const float*)d_in[15];
    const float* h2_w = (const float*)d_in[16];
    const float* h2_b = (const float*)d_in[17];
    float* ws = (float*)d_ws;
    float* out = (float*)d_out;

    k1a_q   <<<Bc*16, 256, 0, stream>>>(node, Wq_w, Wq_b, ws);
    k1b_comb<<<Bc*8,  256, 0, stream>>>(Wk_w, Wk_b, ws);
    k2_h_s  <<<Bc*64, 128, 0, stream>>>(node, edge, emb, Wew, Web, Wa, ws);
    k3_stats<<<Bc,    128, 0, stream>>>(ws);
    k4_mlp  <<<Bc*128,128, 0, stream>>>(node, et_w, et_b, nt_w, nt_b,
                                        h1_w, h1_b, h2_w, h2_b, ws, out);
    k5_nodeout<<<2, 256, 0, stream>>>(ws, out);
}